// Round 1
// baseline (3231.201 us; speedup 1.0000x reference)
//
#include <hip/hip_runtime.h>
#include <hip/hip_bf16.h>
#include <math.h>

// ---------------------------------------------------------------------------
// DGSR layer, MI355X. H = 128 fixed.
// Phase 0: memset outputs + softmax denominators.
// Phase 1: 6 projections O[r] = X[g(r)] @ W.T   (f32 register-tiled GEMM)
// Phase 2: per-edge dots -> exp(logit) (no max-subtraction; logits are ~N(0,2))
//          + atomic denominator accumulation.
// Phase 3: per-edge normalize + atomic scatter of weighted vectors.
// ---------------------------------------------------------------------------

// ----------------------- GEMM: O[r][c] = sum_k X[g(r)][k] * W[c][k] --------
// 64 rows x 128 cols per block, 256 threads, 4x8 per thread, K chunked by 32.
__global__ __launch_bounds__(256) void gemm_xwt_kernel(
    const float* __restrict__ X, const float* __restrict__ W,
    float* __restrict__ O, const int* __restrict__ gidx, int nrows)
{
    __shared__ float Xl[64 * 32];
    __shared__ float Wl[128 * 32];
    const int t  = threadIdx.x;
    const int tx = t & 15;   // col group: cols tx*8 .. tx*8+7
    const int ty = t >> 4;   // row group: rows ty*4 .. ty*4+3
    const int brow = blockIdx.x * 64;

    float acc[4][8];
#pragma unroll
    for (int j = 0; j < 4; ++j)
#pragma unroll
        for (int i = 0; i < 8; ++i) acc[j][i] = 0.f;

    for (int k0 = 0; k0 < 128; k0 += 32) {
        __syncthreads();
        // stage X chunk (64x32): 2 float4 per thread
#pragma unroll
        for (int u = 0; u < 2; ++u) {
            int idx4 = t + u * 256;
            int r  = idx4 >> 3;
            int k4 = idx4 & 7;
            int row = brow + r;
            float4 v = make_float4(0.f, 0.f, 0.f, 0.f);
            if (row < nrows) {
                int g = gidx ? gidx[row] : row;
                v = *(const float4*)(X + (size_t)g * 128 + k0 + k4 * 4);
            }
            int sw = k4 ^ ((r >> 3) & 7);
            *(float4*)(Xl + r * 32 + sw * 4) = v;
        }
        // stage W chunk (128x32): 4 float4 per thread
#pragma unroll
        for (int u = 0; u < 4; ++u) {
            int idx4 = t + u * 256;
            int c  = idx4 >> 3;
            int k4 = idx4 & 7;
            float4 v = *(const float4*)(W + (size_t)c * 128 + k0 + k4 * 4);
            int sw = k4 ^ ((c >> 3) & 7);
            *(float4*)(Wl + c * 32 + sw * 4) = v;
        }
        __syncthreads();
#pragma unroll
        for (int k4 = 0; k4 < 8; ++k4) {
            float4 xv[4], wv[8];
#pragma unroll
            for (int j = 0; j < 4; ++j) {
                int r = ty * 4 + j;
                xv[j] = *(const float4*)(Xl + r * 32 + ((k4 ^ ((r >> 3) & 7)) * 4));
            }
#pragma unroll
            for (int i = 0; i < 8; ++i) {
                int c = tx * 8 + i;
                wv[i] = *(const float4*)(Wl + c * 32 + ((k4 ^ ((c >> 3) & 7)) * 4));
            }
#pragma unroll
            for (int j = 0; j < 4; ++j)
#pragma unroll
                for (int i = 0; i < 8; ++i) {
                    acc[j][i] += xv[j].x * wv[i].x;
                    acc[j][i] += xv[j].y * wv[i].y;
                    acc[j][i] += xv[j].z * wv[i].z;
                    acc[j][i] += xv[j].w * wv[i].w;
                }
        }
    }
#pragma unroll
    for (int j = 0; j < 4; ++j) {
        int row = brow + ty * 4 + j;
        if (row < nrows) {
            float* op = O + (size_t)row * 128 + tx * 8;
            *(float4*)(op)     = make_float4(acc[j][0], acc[j][1], acc[j][2], acc[j][3]);
            *(float4*)(op + 4) = make_float4(acc[j][4], acc[j][5], acc[j][6], acc[j][7]);
        }
    }
}

// ----------------------- Edge pass 1: dots -> exp, denominator atomics ------
__global__ __launch_bounds__(256) void edge_pass1_kernel(
    const float* __restrict__ um_att, const float* __restrict__ im_att,
    const float* __restrict__ last_item, const float* __restrict__ last_user,
    const float* __restrict__ pVui, const float* __restrict__ pKiu,
    const int* __restrict__ ei, int E,
    float* __restrict__ xa, float* __restrict__ xb,
    float* __restrict__ xsa, float* __restrict__ xsb,
    float* __restrict__ sum_a, float* __restrict__ sum_b,
    float* __restrict__ sum_sa, float* __restrict__ sum_sb,
    float inv_sqrt_d)
{
    const int wid  = (int)(((size_t)blockIdx.x * blockDim.x + threadIdx.x) >> 6);
    const int lane = threadIdx.x & 63;
    if (wid >= E) return;
    const int src = ei[wid];
    const int dst = ei[E + wid];

    float2 a  = ((const float2*)(um_att    + (size_t)src * 128))[lane];
    float2 b  = ((const float2*)(im_att    + (size_t)dst * 128))[lane];
    float2 c  = ((const float2*)(last_item + (size_t)src * 128))[lane];
    float2 d  = ((const float2*)(last_user + (size_t)src * 128))[lane];
    float2 pv = ((const float2*)(pVui      + (size_t)wid * 128))[lane];
    float2 pk = ((const float2*)(pKiu      + (size_t)wid * 128))[lane];

    float s0 = a.x * b.x + a.y * b.y;    // um . im
    float s1 = a.x * pv.x + a.y * pv.y;  // um . pVui
    float s2 = b.x * pk.x + b.y * pk.y;  // im . pKiu
    float s3 = c.x * b.x + c.y * b.y;    // last_item . im
    float s4 = d.x * b.x + d.y * b.y;    // last_user . im
#pragma unroll
    for (int off = 32; off > 0; off >>= 1) {
        s0 += __shfl_xor(s0, off);
        s1 += __shfl_xor(s1, off);
        s2 += __shfl_xor(s2, off);
        s3 += __shfl_xor(s3, off);
        s4 += __shfl_xor(s4, off);
    }
    if (lane == 0) {
        float x1 = __expf((s0 + s1) * inv_sqrt_d);
        float x2 = __expf((s0 + s2) * inv_sqrt_d);
        float x3 = __expf(s3 * inv_sqrt_d);
        float x4 = __expf(s4 * inv_sqrt_d);
        xa[wid] = x1; xb[wid] = x2; xsa[wid] = x3; xsb[wid] = x4;
        unsafeAtomicAdd(&sum_a[src],  x1);
        unsafeAtomicAdd(&sum_b[dst],  x2);
        unsafeAtomicAdd(&sum_sa[src], x3);
        unsafeAtomicAdd(&sum_sb[dst], x4);
    }
}

// ----------------------- Edge pass 2: normalize + atomic scatter ------------
__global__ __launch_bounds__(256) void edge_pass2_kernel(
    const float* __restrict__ um_att, const float* __restrict__ im_att,
    const float* __restrict__ um_b, const float* __restrict__ im_b,
    const float* __restrict__ pVui, const float* __restrict__ pKiu,
    const int* __restrict__ ei, int E,
    const float* __restrict__ xa, const float* __restrict__ xb,
    const float* __restrict__ xsa, const float* __restrict__ xsb,
    const float* __restrict__ sum_a, const float* __restrict__ sum_b,
    const float* __restrict__ sum_sa, const float* __restrict__ sum_sb,
    float* __restrict__ hLu, float* __restrict__ hSu,
    float* __restrict__ hLi, float* __restrict__ hSi)
{
    const int wid  = (int)(((size_t)blockIdx.x * blockDim.x + threadIdx.x) >> 6);
    const int lane = threadIdx.x & 63;
    if (wid >= E) return;
    const int src = ei[wid];
    const int dst = ei[E + wid];

    const float alpha = xa[wid]  / sum_a[src];
    const float beta  = xb[wid]  / sum_b[dst];
    const float sal   = xsa[wid] / sum_sa[src];
    const float sbe   = xsb[wid] / sum_sb[dst];

    float2 imbv = ((const float2*)(im_b   + (size_t)dst * 128))[lane];
    float2 pkv  = ((const float2*)(pKiu   + (size_t)wid * 128))[lane];
    float2 umbv = ((const float2*)(um_b   + (size_t)src * 128))[lane];
    float2 pvv  = ((const float2*)(pVui   + (size_t)wid * 128))[lane];
    float2 imav = ((const float2*)(im_att + (size_t)dst * 128))[lane];
    float2 umav = ((const float2*)(um_att + (size_t)src * 128))[lane];

    float* p;
    p = hLu + (size_t)src * 128 + lane * 2;
    unsafeAtomicAdd(p,     alpha * (imbv.x + pkv.x));
    unsafeAtomicAdd(p + 1, alpha * (imbv.y + pkv.y));
    p = hLi + (size_t)dst * 128 + lane * 2;
    unsafeAtomicAdd(p,     beta * (umbv.x + pvv.x));
    unsafeAtomicAdd(p + 1, beta * (umbv.y + pvv.y));
    p = hSu + (size_t)src * 128 + lane * 2;
    unsafeAtomicAdd(p,     sal * (imav.x + 1.f));
    unsafeAtomicAdd(p + 1, sal * (imav.y + 1.f));
    p = hSi + (size_t)dst * 128 + lane * 2;
    unsafeAtomicAdd(p,     sbe * (umav.x + 1.f));
    unsafeAtomicAdd(p + 1, sbe * (umav.y + 1.f));
}

// ---------------------------------------------------------------------------
extern "C" void kernel_launch(void* const* d_in, const int* in_sizes, int n_in,
                              void* d_out, int out_size, void* d_ws, size_t ws_size,
                              hipStream_t stream)
{
    const float* u_emb = (const float*)d_in[0];
    const float* i_emb = (const float*)d_in[1];
    const float* pVui  = (const float*)d_in[2];
    const float* pKiu  = (const float*)d_in[3];
    const float* w1    = (const float*)d_in[4];
    const float* w2    = (const float*)d_in[5];
    const float* w1b   = (const float*)d_in[6];
    const float* w2b   = (const float*)d_in[7];
    const float* w3    = (const float*)d_in[8];
    const float* w4    = (const float*)d_in[9];
    const int* edge_index = (const int*)d_in[10];
    const int* last_u     = (const int*)d_in[11];
    const int* last_i     = (const int*)d_in[12];

    const int U = in_sizes[0] / 128;
    const int I = in_sizes[1] / 128;
    const int E = in_sizes[10] / 2;

    float* ws = (float*)d_ws;
    float* um_att    = ws;  ws += (size_t)U * 128;
    float* im_att    = ws;  ws += (size_t)I * 128;
    float* um_b      = ws;  ws += (size_t)U * 128;
    float* im_b      = ws;  ws += (size_t)I * 128;
    float* last_item = ws;  ws += (size_t)U * 128;
    float* last_user = ws;  ws += (size_t)I * 128;
    float* xa  = ws;  ws += E;
    float* xb  = ws;  ws += E;
    float* xsa = ws;  ws += E;
    float* xsb = ws;  ws += E;
    float* sums   = ws;
    float* sum_a  = sums;
    float* sum_b  = sums + U;
    float* sum_sa = sums + U + I;
    float* sum_sb = sums + U + I + U;

    float* hLu = (float*)d_out;
    float* hSu = hLu + (size_t)U * 128;
    float* hLi = hSu + (size_t)U * 128;
    float* hSi = hLi + (size_t)I * 128;

    hipMemsetAsync(d_out, 0, (size_t)out_size * sizeof(float), stream);
    hipMemsetAsync(sums, 0, (size_t)2 * (U + I) * sizeof(float), stream);

    dim3 blk(256);
    gemm_xwt_kernel<<<(U + 63) / 64, blk, 0, stream>>>(u_emb, w2,  um_att,    nullptr,    U);
    gemm_xwt_kernel<<<(I + 63) / 64, blk, 0, stream>>>(i_emb, w1,  im_att,    nullptr,    I);
    gemm_xwt_kernel<<<(U + 63) / 64, blk, 0, stream>>>(u_emb, w2b, um_b,      nullptr,    U);
    gemm_xwt_kernel<<<(I + 63) / 64, blk, 0, stream>>>(i_emb, w1b, im_b,      nullptr,    I);
    gemm_xwt_kernel<<<(U + 63) / 64, blk, 0, stream>>>(i_emb, w3,  last_item, last_u + U, U);
    gemm_xwt_kernel<<<(I + 63) / 64, blk, 0, stream>>>(u_emb, w4,  last_user, last_i + I, I);

    const float inv_sqrt_d = 1.0f / sqrtf(128.0f);
    const int eblocks = (E + 3) / 4;  // 4 waves (edges) per 256-thread block
    edge_pass1_kernel<<<eblocks, blk, 0, stream>>>(
        um_att, im_att, last_item, last_user, pVui, pKiu, edge_index, E,
        xa, xb, xsa, xsb, sum_a, sum_b, sum_sa, sum_sb, inv_sqrt_d);
    edge_pass2_kernel<<<eblocks, blk, 0, stream>>>(
        um_att, im_att, um_b, im_b, pVui, pKiu, edge_index, E,
        xa, xb, xsa, xsb, sum_a, sum_b, sum_sa, sum_sb,
        hLu, hSu, hLi, hSi);
}

// Round 2
// 1118.395 us; speedup vs baseline: 2.8891x; 2.8891x over previous
//
#include <hip/hip_runtime.h>
#include <hip/hip_bf16.h>
#include <math.h>

// ---------------------------------------------------------------------------
// DGSR layer, MI355X. H = 128 fixed. Scatter-free formulation:
//   1. 6 projections O[r] = X[g(r)] @ W.T (f32 register-tiled GEMM)
//   2. CSR build: degree histogram -> exclusive scan -> edge-id scatter
//   3. gather_u: one wave per user walks its edges; computes logits via
//      shfl_xor dot-reduce, exp (no max-subtraction: logits ~N(0,2)),
//      accumulates numerator vectors + denominators in registers, divides.
//   4. gather_i: symmetric per item.
// No f32 atomics anywhere; pVui/pKiu each streamed exactly twice.
// ---------------------------------------------------------------------------

// ----------------------- GEMM: O[r][c] = sum_k X[g(r)][k] * W[c][k] --------
__global__ __launch_bounds__(256) void gemm_xwt_kernel(
    const float* __restrict__ X, const float* __restrict__ W,
    float* __restrict__ O, const int* __restrict__ gidx, int nrows)
{
    __shared__ float Xl[64 * 32];
    __shared__ float Wl[128 * 32];
    const int t  = threadIdx.x;
    const int tx = t & 15;
    const int ty = t >> 4;
    const int brow = blockIdx.x * 64;

    float acc[4][8];
#pragma unroll
    for (int j = 0; j < 4; ++j)
#pragma unroll
        for (int i = 0; i < 8; ++i) acc[j][i] = 0.f;

    for (int k0 = 0; k0 < 128; k0 += 32) {
        __syncthreads();
#pragma unroll
        for (int u = 0; u < 2; ++u) {
            int idx4 = t + u * 256;
            int r  = idx4 >> 3;
            int k4 = idx4 & 7;
            int row = brow + r;
            float4 v = make_float4(0.f, 0.f, 0.f, 0.f);
            if (row < nrows) {
                int g = gidx ? gidx[row] : row;
                v = *(const float4*)(X + (size_t)g * 128 + k0 + k4 * 4);
            }
            int sw = k4 ^ ((r >> 3) & 7);
            *(float4*)(Xl + r * 32 + sw * 4) = v;
        }
#pragma unroll
        for (int u = 0; u < 4; ++u) {
            int idx4 = t + u * 256;
            int c  = idx4 >> 3;
            int k4 = idx4 & 7;
            float4 v = *(const float4*)(W + (size_t)c * 128 + k0 + k4 * 4);
            int sw = k4 ^ ((c >> 3) & 7);
            *(float4*)(Wl + c * 32 + sw * 4) = v;
        }
        __syncthreads();
#pragma unroll
        for (int k4 = 0; k4 < 8; ++k4) {
            float4 xv[4], wv[8];
#pragma unroll
            for (int j = 0; j < 4; ++j) {
                int r = ty * 4 + j;
                xv[j] = *(const float4*)(Xl + r * 32 + ((k4 ^ ((r >> 3) & 7)) * 4));
            }
#pragma unroll
            for (int i = 0; i < 8; ++i) {
                int c = tx * 8 + i;
                wv[i] = *(const float4*)(Wl + c * 32 + ((k4 ^ ((c >> 3) & 7)) * 4));
            }
#pragma unroll
            for (int j = 0; j < 4; ++j)
#pragma unroll
                for (int i = 0; i < 8; ++i) {
                    acc[j][i] += xv[j].x * wv[i].x;
                    acc[j][i] += xv[j].y * wv[i].y;
                    acc[j][i] += xv[j].z * wv[i].z;
                    acc[j][i] += xv[j].w * wv[i].w;
                }
        }
    }
#pragma unroll
    for (int j = 0; j < 4; ++j) {
        int row = brow + ty * 4 + j;
        if (row < nrows) {
            float* op = O + (size_t)row * 128 + tx * 8;
            *(float4*)(op)     = make_float4(acc[j][0], acc[j][1], acc[j][2], acc[j][3]);
            *(float4*)(op + 4) = make_float4(acc[j][4], acc[j][5], acc[j][6], acc[j][7]);
        }
    }
}

// ----------------------- CSR build ------------------------------------------
__global__ __launch_bounds__(256) void hist_kernel(
    const int* __restrict__ ei, int E,
    int* __restrict__ deg_u, int* __restrict__ deg_i)
{
    int e = blockIdx.x * 256 + threadIdx.x;
    if (e < E) {
        atomicAdd(&deg_u[ei[e]], 1);
        atomicAdd(&deg_i[ei[E + e]], 1);
    }
}

// One block per array: blockIdx 0 -> user degrees, 1 -> item degrees.
__global__ __launch_bounds__(1024) void scan_kernel(
    const int* __restrict__ deg_u, int* __restrict__ off_u, int* __restrict__ cur_u, int nu,
    const int* __restrict__ deg_i, int* __restrict__ off_i, int* __restrict__ cur_i, int ni)
{
    const int* deg = (blockIdx.x == 0) ? deg_u : deg_i;
    int* off       = (blockIdx.x == 0) ? off_u : off_i;
    int* cur       = (blockIdx.x == 0) ? cur_u : cur_i;
    const int n    = (blockIdx.x == 0) ? nu : ni;

    __shared__ int sh[1024];
    const int t = threadIdx.x;
    int carry = 0;
    for (int base = 0; base < n; base += 1024) {
        int i = base + t;
        int v = (i < n) ? deg[i] : 0;
        sh[t] = v;
        __syncthreads();
#pragma unroll
        for (int o = 1; o < 1024; o <<= 1) {
            int add = (t >= o) ? sh[t - o] : 0;
            __syncthreads();
            sh[t] += add;
            __syncthreads();
        }
        int excl = carry + sh[t] - v;
        if (i < n) { off[i] = excl; cur[i] = excl; }
        int total = sh[1023];
        __syncthreads();
        carry += total;
    }
    if (t == 0) off[n] = carry;
}

__global__ __launch_bounds__(256) void scatter_ids_kernel(
    const int* __restrict__ ei, int E,
    int* __restrict__ cur_u, int* __restrict__ cur_i,
    int* __restrict__ eu_list, int* __restrict__ ei_list)
{
    int e = blockIdx.x * 256 + threadIdx.x;
    if (e < E) {
        int pu = atomicAdd(&cur_u[ei[e]], 1);
        eu_list[pu] = e;
        int pi = atomicAdd(&cur_i[ei[E + e]], 1);
        ei_list[pi] = e;
    }
}

// ----------------------- Gather passes --------------------------------------
__global__ __launch_bounds__(256) void gather_u_kernel(
    const float* __restrict__ um_att, const float* __restrict__ im_att,
    const float* __restrict__ im_b, const float* __restrict__ last_item,
    const float* __restrict__ pVui, const float* __restrict__ pKiu,
    const int* __restrict__ ei, int E,
    const int* __restrict__ off_u, const int* __restrict__ eu_list,
    float* __restrict__ hLu, float* __restrict__ hSu, int U, float inv_sqrt_d)
{
    const int wid  = (int)((blockIdx.x * blockDim.x + threadIdx.x) >> 6);
    const int lane = threadIdx.x & 63;
    if (wid >= U) return;

    const float2 ua = ((const float2*)(um_att    + (size_t)wid * 128))[lane];
    const float2 li = ((const float2*)(last_item + (size_t)wid * 128))[lane];

    float2 acc1 = make_float2(0.f, 0.f), acc3 = make_float2(0.f, 0.f);
    float s1 = 0.f, s3 = 0.f;
    const int e0 = off_u[wid], e1 = off_u[wid + 1];
    for (int e = e0; e < e1; ++e) {
        int eid = eu_list[e];
        int dst = ei[E + eid];
        float2 ia = ((const float2*)(im_att + (size_t)dst * 128))[lane];
        float2 pv = ((const float2*)(pVui   + (size_t)eid * 128))[lane];
        float2 pk = ((const float2*)(pKiu   + (size_t)eid * 128))[lane];
        float2 ib = ((const float2*)(im_b   + (size_t)dst * 128))[lane];

        float d0 = ua.x * ia.x + ua.y * ia.y;
        float d1 = ua.x * pv.x + ua.y * pv.y;
        float d3 = li.x * ia.x + li.y * ia.y;
#pragma unroll
        for (int o = 32; o > 0; o >>= 1) {
            d0 += __shfl_xor(d0, o);
            d1 += __shfl_xor(d1, o);
            d3 += __shfl_xor(d3, o);
        }
        float x1 = __expf((d0 + d1) * inv_sqrt_d);
        float x3 = __expf(d3 * inv_sqrt_d);
        acc1.x += x1 * (ib.x + pk.x); acc1.y += x1 * (ib.y + pk.y);
        acc3.x += x3 * (ia.x + 1.f);  acc3.y += x3 * (ia.y + 1.f);
        s1 += x1; s3 += x3;
    }
    float r1 = (s1 > 0.f) ? 1.f / s1 : 0.f;
    float r3 = (s3 > 0.f) ? 1.f / s3 : 0.f;
    ((float2*)(hLu + (size_t)wid * 128))[lane] = make_float2(acc1.x * r1, acc1.y * r1);
    ((float2*)(hSu + (size_t)wid * 128))[lane] = make_float2(acc3.x * r3, acc3.y * r3);
}

__global__ __launch_bounds__(256) void gather_i_kernel(
    const float* __restrict__ um_att, const float* __restrict__ im_att,
    const float* __restrict__ um_b, const float* __restrict__ last_user,
    const float* __restrict__ pVui, const float* __restrict__ pKiu,
    const int* __restrict__ ei, int E,
    const int* __restrict__ off_i, const int* __restrict__ ei_list,
    float* __restrict__ hLi, float* __restrict__ hSi, int I, float inv_sqrt_d)
{
    const int wid  = (int)((blockIdx.x * blockDim.x + threadIdx.x) >> 6);
    const int lane = threadIdx.x & 63;
    if (wid >= I) return;

    const float2 ia = ((const float2*)(im_att + (size_t)wid * 128))[lane];

    float2 acc2 = make_float2(0.f, 0.f), acc4 = make_float2(0.f, 0.f);
    float s2 = 0.f, s4 = 0.f;
    const int e0 = off_i[wid], e1 = off_i[wid + 1];
    for (int e = e0; e < e1; ++e) {
        int eid = ei_list[e];
        int src = ei[eid];
        float2 ua = ((const float2*)(um_att    + (size_t)src * 128))[lane];
        float2 ub = ((const float2*)(um_b      + (size_t)src * 128))[lane];
        float2 lu = ((const float2*)(last_user + (size_t)src * 128))[lane];
        float2 pv = ((const float2*)(pVui      + (size_t)eid * 128))[lane];
        float2 pk = ((const float2*)(pKiu      + (size_t)eid * 128))[lane];

        float d0 = ua.x * ia.x + ua.y * ia.y;
        float d2 = ia.x * pk.x + ia.y * pk.y;
        float d4 = lu.x * ia.x + lu.y * ia.y;
#pragma unroll
        for (int o = 32; o > 0; o >>= 1) {
            d0 += __shfl_xor(d0, o);
            d2 += __shfl_xor(d2, o);
            d4 += __shfl_xor(d4, o);
        }
        float x2 = __expf((d0 + d2) * inv_sqrt_d);
        float x4 = __expf(d4 * inv_sqrt_d);
        acc2.x += x2 * (ub.x + pv.x); acc2.y += x2 * (ub.y + pv.y);
        acc4.x += x4 * (ua.x + 1.f);  acc4.y += x4 * (ua.y + 1.f);
        s2 += x2; s4 += x4;
    }
    float r2 = (s2 > 0.f) ? 1.f / s2 : 0.f;
    float r4 = (s4 > 0.f) ? 1.f / s4 : 0.f;
    ((float2*)(hLi + (size_t)wid * 128))[lane] = make_float2(acc2.x * r2, acc2.y * r2);
    ((float2*)(hSi + (size_t)wid * 128))[lane] = make_float2(acc4.x * r4, acc4.y * r4);
}

// ---------------------------------------------------------------------------
extern "C" void kernel_launch(void* const* d_in, const int* in_sizes, int n_in,
                              void* d_out, int out_size, void* d_ws, size_t ws_size,
                              hipStream_t stream)
{
    const float* u_emb = (const float*)d_in[0];
    const float* i_emb = (const float*)d_in[1];
    const float* pVui  = (const float*)d_in[2];
    const float* pKiu  = (const float*)d_in[3];
    const float* w1    = (const float*)d_in[4];
    const float* w2    = (const float*)d_in[5];
    const float* w1b   = (const float*)d_in[6];
    const float* w2b   = (const float*)d_in[7];
    const float* w3    = (const float*)d_in[8];
    const float* w4    = (const float*)d_in[9];
    const int* edge_index = (const int*)d_in[10];
    const int* last_u     = (const int*)d_in[11];
    const int* last_i     = (const int*)d_in[12];

    const int U = in_sizes[0] / 128;
    const int I = in_sizes[1] / 128;
    const int E = in_sizes[10] / 2;

    float* ws = (float*)d_ws;
    float* um_att    = ws;  ws += (size_t)U * 128;
    float* im_att    = ws;  ws += (size_t)I * 128;
    float* um_b      = ws;  ws += (size_t)U * 128;
    float* im_b      = ws;  ws += (size_t)I * 128;
    float* last_item = ws;  ws += (size_t)U * 128;
    float* last_user = ws;  ws += (size_t)I * 128;
    int* ip = (int*)ws;
    int* deg_u   = ip;  ip += U;
    int* deg_i   = ip;  ip += I;
    int* off_u   = ip;  ip += U + 1;
    int* off_i   = ip;  ip += I + 1;
    int* cur_u   = ip;  ip += U;
    int* cur_i   = ip;  ip += I;
    int* eu_list = ip;  ip += E;
    int* ei_list = ip;  ip += E;

    float* hLu = (float*)d_out;
    float* hSu = hLu + (size_t)U * 128;
    float* hLi = hSu + (size_t)U * 128;
    float* hSi = hLi + (size_t)I * 128;

    hipMemsetAsync(deg_u, 0, (size_t)(U + I) * sizeof(int), stream);

    dim3 blk(256);
    const int eblk = (E + 255) / 256;
    hist_kernel<<<eblk, blk, 0, stream>>>(edge_index, E, deg_u, deg_i);
    scan_kernel<<<2, 1024, 0, stream>>>(deg_u, off_u, cur_u, U, deg_i, off_i, cur_i, I);
    scatter_ids_kernel<<<eblk, blk, 0, stream>>>(edge_index, E, cur_u, cur_i, eu_list, ei_list);

    gemm_xwt_kernel<<<(U + 63) / 64, blk, 0, stream>>>(u_emb, w2,  um_att,    nullptr,    U);
    gemm_xwt_kernel<<<(I + 63) / 64, blk, 0, stream>>>(i_emb, w1,  im_att,    nullptr,    I);
    gemm_xwt_kernel<<<(U + 63) / 64, blk, 0, stream>>>(u_emb, w2b, um_b,      nullptr,    U);
    gemm_xwt_kernel<<<(I + 63) / 64, blk, 0, stream>>>(i_emb, w1b, im_b,      nullptr,    I);
    gemm_xwt_kernel<<<(U + 63) / 64, blk, 0, stream>>>(i_emb, w3,  last_item, last_u + U, U);
    gemm_xwt_kernel<<<(I + 63) / 64, blk, 0, stream>>>(u_emb, w4,  last_user, last_i + I, I);

    const float inv_sqrt_d = 1.0f / sqrtf(128.0f);
    gather_u_kernel<<<(U + 3) / 4, blk, 0, stream>>>(
        um_att, im_att, im_b, last_item, pVui, pKiu, edge_index, E,
        off_u, eu_list, hLu, hSu, U, inv_sqrt_d);
    gather_i_kernel<<<(I + 3) / 4, blk, 0, stream>>>(
        um_att, im_att, um_b, last_user, pVui, pKiu, edge_index, E,
        off_i, ei_list, hLi, hSi, I, inv_sqrt_d);
}